// Round 10
// baseline (97.153 us; speedup 1.0000x reference)
//
#include <hip/hip_runtime.h>
#include <hip/hip_fp16.h>

typedef float f32x2 __attribute__((ext_vector_type(2)));

#define NA    128
#define NPTS  256
#define DD    16
#define MMI   255    // valid inc rows 0..254
#define NSTEP 318    // 255 + 63 wavefront steps
#define RINGN 128    // ring slots
#define NPAIR 64     // slot pairs
#define PH    16     // steps per phase; 20 phases

// whole-wave shift-down-by-1 via DPP; lane 0 keeps `boundary`.
__device__ __forceinline__ float wave_shr1(float x, float boundary) {
    int r = __builtin_amdgcn_update_dpp(
        __builtin_bit_cast(int, boundary),
        __builtin_bit_cast(int, x),
        0x138 /* wave_shr:1 */, 0xF, 0xF, false);
    return __builtin_bit_cast(float, r);
}

__device__ __forceinline__ unsigned int pkh2(float a, float b) {
#if __has_builtin(__builtin_amdgcn_cvt_pkrtz)
    return __builtin_bit_cast(unsigned int, __builtin_amdgcn_cvt_pkrtz(a, b));
#else
    _Float16 x = (_Float16)a, y = (_Float16)b;
    unsigned short lo = __builtin_bit_cast(unsigned short, x);
    unsigned short hi = __builtin_bit_cast(unsigned short, y);
    return (unsigned int)lo | ((unsigned int)hi << 16);
#endif
}

// One block (4 waves) per (pair,batch) problem.
// Wave 0 = PDE consumer: lane l owns cols 4l..4l+3, step s handles row s-l.
//   Reads fp16 skew-rows from paired LDS ring: 1 ds_read_b128 per 2 steps,
//   loaded one FULL PHASE ahead (zero exposed LDS latency).
// Waves 1-3 = producers (f32 dots, R7 numerics): write g row r as fp16 to
//   skew slot (r+lane)&127, running TWO phases ahead of the consumer.
// Boundary: ring pre-zeroed + rows>=255 written as zeros; g=0 => c1=c2=1
// identity keeps K=1 outside the active triangle (proven R4-R9).
__global__ __launch_bounds__(256)
void sig_fused(const float* __restrict__ X, const float* __restrict__ Y,
               float* __restrict__ out) {
    const int pid  = blockIdx.x;
    const int pair = pid >> 7;     // 0: XX, 1: YY, 2: XY
    const int a    = pid & 127;
    const float* U = (pair == 1) ? Y : X;   // g rows
    const float* V = (pair == 0) ? X : Y;   // g cols
    const float  w = (pair == 2) ? (-2.0f / (float)NA) : (1.0f / (float)NA);
    U += (size_t)a * (NPTS * DD);
    V += (size_t)a * (NPTS * DD);

    __shared__ float dU[256][16];            // 16 KB f32 (row 255 = 0)
    __shared__ uint2 ring2[NPAIR][64][2];    // 64 KB fp16 ring, paired slots

    const int tid  = threadIdx.x;
    const int wid  = tid >> 6;
    const int lane = tid & 63;

    // ---- stage dU = f32 diff(U); thread t -> row t (row 255 zero) ----
    {
        float4 v0 = make_float4(0.f,0.f,0.f,0.f), v1 = v0, v2 = v0, v3 = v0;
        if (tid < MMI) {
            const float4* Ua = (const float4*)(U + (size_t)tid * DD);
            float4 lo, hi;
            lo = Ua[0]; hi = Ua[4];
            v0 = make_float4(hi.x-lo.x, hi.y-lo.y, hi.z-lo.z, hi.w-lo.w);
            lo = Ua[1]; hi = Ua[5];
            v1 = make_float4(hi.x-lo.x, hi.y-lo.y, hi.z-lo.z, hi.w-lo.w);
            lo = Ua[2]; hi = Ua[6];
            v2 = make_float4(hi.x-lo.x, hi.y-lo.y, hi.z-lo.z, hi.w-lo.w);
            lo = Ua[3]; hi = Ua[7];
            v3 = make_float4(hi.x-lo.x, hi.y-lo.y, hi.z-lo.z, hi.w-lo.w);
        }
        float4* dp = (float4*)&dU[tid][0];
        dp[0] = v0; dp[1] = v1; dp[2] = v2; dp[3] = v3;
    }
    // ---- zero ring ----
    {
        const uint4 z = {0u, 0u, 0u, 0u};
        uint4* rp = (uint4*)&ring2[0][0][0];     // 4096 uint4
        #pragma unroll
        for (int m = 0; m < 16; ++m) rp[tid + 256*m] = z;
    }

    // ---- producer dV columns (f32 regs): cols 4*lane..4*lane+3 ----
    f32x2 dv[4][8];
    if (wid != 0) {
        #pragma unroll
        for (int k = 0; k < 4; ++k) {
            int j = 4*lane + k;
            const bool valid = (j < MMI);
            const int jj = valid ? j : 0;
            const float2* Va = (const float2*)(V + (size_t)jj * DD);
            const float2* Vb = (const float2*)(V + (size_t)(jj + 1) * DD);
            #pragma unroll
            for (int q = 0; q < 8; ++q) {
                float2 lo = Va[q], hi = Vb[q];
                dv[k][q] = valid ? f32x2{hi.x - lo.x, hi.y - lo.y}
                                 : f32x2{0.f, 0.f};
            }
        }
    }
    __syncthreads();

    // ---- producer: g row r (f32 dots) -> fp16 skew slot ----
    auto produce = [&](int r) {
        int slot = (r + lane) & (RINGN - 1);
        uint2 wv = make_uint2(0u, 0u);
        if (r < MMI) {
            const float4* up = (const float4*)&dU[r][0];   // uniform broadcast
            float4 u0 = up[0], u1 = up[1], u2 = up[2], u3 = up[3];
            f32x2 uu[8] = {
                f32x2{u0.x,u0.y}, f32x2{u0.z,u0.w},
                f32x2{u1.x,u1.y}, f32x2{u1.z,u1.w},
                f32x2{u2.x,u2.y}, f32x2{u2.z,u2.w},
                f32x2{u3.x,u3.y}, f32x2{u3.z,u3.w}};
            f32x2 a0 = uu[0]*dv[0][0], a1 = uu[0]*dv[1][0];
            f32x2 a2 = uu[0]*dv[2][0], a3 = uu[0]*dv[3][0];
            #pragma unroll
            for (int q = 1; q < 8; ++q) {
                a0 = __builtin_elementwise_fma(uu[q], dv[0][q], a0);
                a1 = __builtin_elementwise_fma(uu[q], dv[1][q], a1);
                a2 = __builtin_elementwise_fma(uu[q], dv[2][q], a2);
                a3 = __builtin_elementwise_fma(uu[q], dv[3][q], a3);
            }
            wv.x = pkh2(a0.x + a0.y, a1.x + a1.y);
            wv.y = pkh2(a2.x + a2.y, a3.x + a3.y);
        }
        ring2[slot >> 1][lane][slot & 1] = wv;
    };
    auto produce_range = [&](int rb) {
        int re = rb + PH; if (re > NSTEP) re = NSTEP;
        for (int r = rb + wid - 1; r < re; r += 3) produce(r);
    };

    // ---- consumer state ----
    float kup0 = 1.f, kup1 = 1.f, kup2 = 1.f, kup3 = 1.f;
    float shnew = 1.f, shprev = 1.f;

    auto STEP = [&](unsigned int bx, unsigned int by) {
        float2 f01 = __half22float2(__builtin_bit_cast(__half2, bx));
        float2 f23 = __half22float2(__builtin_bit_cast(__half2, by));
        f32x2 g01 = f32x2{f01.x, f01.y}, g23 = f32x2{f23.x, f23.y};
        f32x2 e01 = (g01 * g01) * f32x2{1.f/12.f, 1.f/12.f};
        f32x2 e23 = (g23 * g23) * f32x2{1.f/12.f, 1.f/12.f};
        f32x2 c1a = __builtin_elementwise_fma(g01, f32x2{0.5f, 0.5f},
                                              f32x2{1.f, 1.f}) + e01;
        f32x2 c1b = __builtin_elementwise_fma(g23, f32x2{0.5f, 0.5f},
                                              f32x2{1.f, 1.f}) + e23;
        f32x2 c2a = f32x2{1.f, 1.f} - e01;
        f32x2 c2b = f32x2{1.f, 1.f} - e23;
        const float left = shnew, upleft = shprev;
        const float pre0 = fmaf(kup0, c1a.x, -(upleft * c2a.x));
        const float pre1 = fmaf(kup1, c1a.y, -(kup0 * c2a.y));
        const float pre2 = fmaf(kup2, c1b.x, -(kup1 * c2b.x));
        const float pre3 = fmaf(kup3, c1b.y, -(kup2 * c2b.y));
        const float t0 = fmaf(left, c1a.x, pre0);
        const float t1 = fmaf(t0,   c1a.y, pre1);
        const float t2 = fmaf(t1,   c1b.x, pre2);
        const float t3 = fmaf(t2,   c1b.y, pre3);
        shprev = shnew;
        kup0 = t0; kup1 = t1; kup2 = t2; kup3 = t3;
        shnew = wave_shr1(t3, 1.0f);
    };

    const char* rbase = (const char*)&ring2[0][lane][0];
    // load 8 pairs (16 slots) starting at pair pb (pb multiple of 8, no wrap)
    auto LOADP = [&](int pb, uint4* dst) {
        const char* p = rbase + (size_t)pb * 1024;
        #pragma unroll
        for (int i = 0; i < 8; ++i) dst[i] = *(const uint4*)(p + i * 1024);
    };
    auto STEP16 = [&](const uint4* c) {
        #pragma unroll
        for (int i = 0; i < 8; ++i) { STEP(c[i].x, c[i].y); STEP(c[i].z, c[i].w); }
    };

    // ---- prologue: producers write rows [0,32) ----
    if (wid != 0) {
        for (int r = wid - 1; r < 2 * PH; r += 3) produce(r);
    }
    __syncthreads();

    uint4 A[8], B[8];
    if (wid == 0) LOADP(0, A);   // slots [0,16): one exposed wait, once

    // ---- phases 0..17 (pairs of phases; A/B statically alternated) ----
    for (int h = 0; h < 9; ++h) {
        const int q0 = 2 * h, q1 = 2 * h + 1;
        if (wid == 0) { LOADP((8*q0 + 8) & 63, B); STEP16(A); }
        else          produce_range(16*q0 + 32);
        __syncthreads();
        if (wid == 0) { LOADP((8*q1 + 8) & 63, A); STEP16(B); }
        else          produce_range(16*q1 + 32);
        __syncthreads();
    }
    // ---- phase 18: steps [288,304); load slots [304,320) ----
    if (wid == 0) { LOADP((8*18 + 8) & 63, B); STEP16(A); }
    else          produce_range(16*18 + 32);   // rows >= 320: none
    __syncthreads();
    // ---- phase 19: steps [304,318) = 14 steps (7 pairs) ----
    if (wid == 0) {
        #pragma unroll
        for (int i = 0; i < 7; ++i) { STEP(B[i].x, B[i].y); STEP(B[i].z, B[i].w); }
        // K[255][255] = lane 63's kup2 (col j = 4*63+2+1 = 255)
        if (lane == 63) atomicAdd(out, w * kup2);
    }
}

extern "C" void kernel_launch(void* const* d_in, const int* in_sizes, int n_in,
                              void* d_out, int out_size, void* d_ws, size_t ws_size,
                              hipStream_t stream) {
    const float* X = (const float*)d_in[0];
    const float* Y = (const float*)d_in[1];
    float* out = (float*)d_out;
    hipMemsetAsync(out, 0, sizeof(float), stream);
    sig_fused<<<dim3(3 * NA), dim3(256), 0, stream>>>(X, Y, out);
}

// Round 11
// 95.482 us; speedup vs baseline: 1.0175x; 1.0175x over previous
//
#include <hip/hip_runtime.h>
#include <hip/hip_fp16.h>

typedef float f32x2 __attribute__((ext_vector_type(2)));

#define NA    128
#define NPTS  256
#define DD    16
#define MMI   255    // valid inc rows 0..254 (row 255 is the zero row)
#define NSTEP 318    // 255 + 63 wavefront steps
#define RINGN 128    // ring slots
#define NPAIR 64     // slot pairs
#define PH    16     // steps per phase; 20 phases

// whole-wave shift-down-by-1 via DPP; lane 0 keeps `boundary`.
__device__ __forceinline__ float wave_shr1(float x, float boundary) {
    int r = __builtin_amdgcn_update_dpp(
        __builtin_bit_cast(int, boundary),
        __builtin_bit_cast(int, x),
        0x138 /* wave_shr:1 */, 0xF, 0xF, false);
    return __builtin_bit_cast(float, r);
}

__device__ __forceinline__ unsigned int pkh2(float a, float b) {
#if __has_builtin(__builtin_amdgcn_cvt_pkrtz)
    return __builtin_bit_cast(unsigned int, __builtin_amdgcn_cvt_pkrtz(a, b));
#else
    _Float16 x = (_Float16)a, y = (_Float16)b;
    unsigned short lo = __builtin_bit_cast(unsigned short, x);
    unsigned short hi = __builtin_bit_cast(unsigned short, y);
    return (unsigned int)lo | ((unsigned int)hi << 16);
#endif
}

// One block (4 waves) per (pair,batch) problem.
// Wave 0 = PDE consumer (s_setprio(1)): lane l owns cols 4l..4l+3, step s row s-l.
//   Paired fp16 ring reads (1 ds_read_b128 / 2 steps), registers loaded one
//   full phase ahead.
// Waves 1-3 = producers, STATIC 2-ahead pipelined (dU row r+3 loads under the
//   compute of row r), f32 dots, fp16 skew-slot writes, 2 phases ahead.
// Boundary: ring pre-zeroed; dU row 255 = 0 so rows >= 255 produce g = 0;
// g=0 => c1=1, e=0 => identity step keeps K=1 outside the triangle (R4-R10).
__global__ __launch_bounds__(256)
void sig_fused(const float* __restrict__ X, const float* __restrict__ Y,
               float* __restrict__ out) {
    const int pid  = blockIdx.x;
    const int pair = pid >> 7;     // 0: XX, 1: YY, 2: XY
    const int a    = pid & 127;
    const float* U = (pair == 1) ? Y : X;   // g rows
    const float* V = (pair == 0) ? X : Y;   // g cols
    const float  w = (pair == 2) ? (-2.0f / (float)NA) : (1.0f / (float)NA);
    U += (size_t)a * (NPTS * DD);
    V += (size_t)a * (NPTS * DD);

    __shared__ float dU[256][16];            // 16 KB f32 (row 255 = 0)
    __shared__ uint2 ring2[NPAIR][64][2];    // 64 KB fp16 ring, paired slots

    const int tid  = threadIdx.x;
    const int wid  = tid >> 6;
    const int lane = tid & 63;

    // ---- stage dU = f32 diff(U); thread t -> row t (row 255 zero) ----
    {
        float4 v0 = make_float4(0.f,0.f,0.f,0.f), v1 = v0, v2 = v0, v3 = v0;
        if (tid < MMI) {
            const float4* Ua = (const float4*)(U + (size_t)tid * DD);
            float4 lo, hi;
            lo = Ua[0]; hi = Ua[4];
            v0 = make_float4(hi.x-lo.x, hi.y-lo.y, hi.z-lo.z, hi.w-lo.w);
            lo = Ua[1]; hi = Ua[5];
            v1 = make_float4(hi.x-lo.x, hi.y-lo.y, hi.z-lo.z, hi.w-lo.w);
            lo = Ua[2]; hi = Ua[6];
            v2 = make_float4(hi.x-lo.x, hi.y-lo.y, hi.z-lo.z, hi.w-lo.w);
            lo = Ua[3]; hi = Ua[7];
            v3 = make_float4(hi.x-lo.x, hi.y-lo.y, hi.z-lo.z, hi.w-lo.w);
        }
        float4* dp = (float4*)&dU[tid][0];
        dp[0] = v0; dp[1] = v1; dp[2] = v2; dp[3] = v3;
    }
    // ---- zero ring ----
    {
        const uint4 z = {0u, 0u, 0u, 0u};
        uint4* rp = (uint4*)&ring2[0][0][0];     // 4096 uint4
        #pragma unroll
        for (int m = 0; m < 16; ++m) rp[tid + 256*m] = z;
    }

    // ---- producer dV columns (f32 regs): cols 4*lane..4*lane+3 ----
    f32x2 dv[4][8];
    if (wid != 0) {
        #pragma unroll
        for (int k = 0; k < 4; ++k) {
            int j = 4*lane + k;
            const bool valid = (j < MMI);
            const int jj = valid ? j : 0;
            const float2* Va = (const float2*)(V + (size_t)jj * DD);
            const float2* Vb = (const float2*)(V + (size_t)(jj + 1) * DD);
            #pragma unroll
            for (int q = 0; q < 8; ++q) {
                float2 lo = Va[q], hi = Vb[q];
                dv[k][q] = valid ? f32x2{hi.x - lo.x, hi.y - lo.y}
                                 : f32x2{0.f, 0.f};
            }
        }
    } else {
        __builtin_amdgcn_s_setprio(1);   // consumer = critical path (T5)
    }
    __syncthreads();

    // ---- producer primitives ----
    auto LOADU = [&](int r, f32x2* uu) {
        int rc = (r < MMI) ? r : 255;              // row 255 = zeros
        const float4* up = (const float4*)&dU[rc][0];
        float4 u0 = up[0], u1 = up[1], u2 = up[2], u3 = up[3];
        uu[0] = f32x2{u0.x,u0.y}; uu[1] = f32x2{u0.z,u0.w};
        uu[2] = f32x2{u1.x,u1.y}; uu[3] = f32x2{u1.z,u1.w};
        uu[4] = f32x2{u2.x,u2.y}; uu[5] = f32x2{u2.z,u2.w};
        uu[6] = f32x2{u3.x,u3.y}; uu[7] = f32x2{u3.z,u3.w};
    };
    auto CW = [&](int r, const f32x2* uu) {        // compute g row r + write
        f32x2 a0 = uu[0]*dv[0][0], a1 = uu[0]*dv[1][0];
        f32x2 a2 = uu[0]*dv[2][0], a3 = uu[0]*dv[3][0];
        #pragma unroll
        for (int q = 1; q < 8; ++q) {
            a0 = __builtin_elementwise_fma(uu[q], dv[0][q], a0);
            a1 = __builtin_elementwise_fma(uu[q], dv[1][q], a1);
            a2 = __builtin_elementwise_fma(uu[q], dv[2][q], a2);
            a3 = __builtin_elementwise_fma(uu[q], dv[3][q], a3);
        }
        uint2 wv;
        wv.x = pkh2(a0.x + a0.y, a1.x + a1.y);
        wv.y = pkh2(a2.x + a2.y, a3.x + a3.y);
        int slot = (r + lane) & (RINGN - 1);
        ring2[slot >> 1][lane][slot & 1] = wv;
    };
    // 16 rows [rb, rb+PH) split by wave, static 2-ahead pipeline (<=6 rows/wave)
    auto produce_piped = [&](int rb) {
        const int re = (rb + PH < NSTEP) ? rb + PH : NSTEP;
        const int r0 = rb + wid - 1;
        const int r1 = r0 + 3, r2 = r0 + 6, r3 = r0 + 9, r4 = r0 + 12, r5 = r0 + 15;
        const bool b0 = r0 < re, b1 = r1 < re, b2 = r2 < re,
                   b3 = r3 < re, b4 = r4 < re, b5 = r5 < re;
        f32x2 uA[8], uB[8];
        if (b0) LOADU(r0, uA);
        if (b1) LOADU(r1, uB);
        if (b0) CW(r0, uA);
        if (b2) LOADU(r2, uA);
        if (b1) CW(r1, uB);
        if (b3) LOADU(r3, uB);
        if (b2) CW(r2, uA);
        if (b4) LOADU(r4, uA);
        if (b3) CW(r3, uB);
        if (b5) LOADU(r5, uB);
        if (b4) CW(r4, uA);
        if (b5) CW(r5, uB);
    };

    // ---- consumer state ----
    float kup0 = 1.f, kup1 = 1.f, kup2 = 1.f, kup3 = 1.f;
    float shnew = 1.f, shprev = 1.f;

    // t = (left+kup)*c1 - kd*(1-e);  pre = fma(kd, e, fma(kup, c1, -kd))
    auto STEP = [&](unsigned int bx, unsigned int by) {
        float2 f01 = __half22float2(__builtin_bit_cast(__half2, bx));
        float2 f23 = __half22float2(__builtin_bit_cast(__half2, by));
        f32x2 g01 = f32x2{f01.x, f01.y}, g23 = f32x2{f23.x, f23.y};
        f32x2 e01 = (g01 * g01) * f32x2{1.f/12.f, 1.f/12.f};
        f32x2 e23 = (g23 * g23) * f32x2{1.f/12.f, 1.f/12.f};
        f32x2 c1a = __builtin_elementwise_fma(g01, f32x2{0.5f, 0.5f},
                                              f32x2{1.f, 1.f}) + e01;
        f32x2 c1b = __builtin_elementwise_fma(g23, f32x2{0.5f, 0.5f},
                                              f32x2{1.f, 1.f}) + e23;
        const float left = shnew, upleft = shprev;
        const float pre0 = fmaf(upleft, e01.x, fmaf(kup0, c1a.x, -upleft));
        const float pre1 = fmaf(kup0,   e01.y, fmaf(kup1, c1a.y, -kup0));
        const float pre2 = fmaf(kup1,   e23.x, fmaf(kup2, c1b.x, -kup1));
        const float pre3 = fmaf(kup2,   e23.y, fmaf(kup3, c1b.y, -kup2));
        const float t0 = fmaf(left, c1a.x, pre0);
        const float t1 = fmaf(t0,   c1a.y, pre1);
        const float t2 = fmaf(t1,   c1b.x, pre2);
        const float t3 = fmaf(t2,   c1b.y, pre3);
        shprev = shnew;
        kup0 = t0; kup1 = t1; kup2 = t2; kup3 = t3;
        shnew = wave_shr1(t3, 1.0f);
    };

    const char* rbase = (const char*)&ring2[0][lane][0];
    auto LOADP = [&](int pb, uint4* dst) {     // 8 pairs (16 slots), no wrap
        const char* p = rbase + (size_t)pb * 1024;
        #pragma unroll
        for (int i = 0; i < 8; ++i) dst[i] = *(const uint4*)(p + i * 1024);
    };
    auto STEP16 = [&](const uint4* c) {
        #pragma unroll
        for (int i = 0; i < 8; ++i) { STEP(c[i].x, c[i].y); STEP(c[i].z, c[i].w); }
    };

    // ---- prologue: producers write rows [0,32) ----
    if (wid != 0) { produce_piped(0); produce_piped(PH); }
    __syncthreads();

    uint4 A[8], B[8];
    if (wid == 0) LOADP(0, A);   // slots [0,16): single exposed wait, once

    // ---- phases 0..17 (A/B statically alternated) ----
    for (int h = 0; h < 9; ++h) {
        const int q0 = 2 * h, q1 = 2 * h + 1;
        if (wid == 0) { LOADP((8*q0 + 8) & 63, B); STEP16(A); }
        else          produce_piped(16*q0 + 32);
        __syncthreads();
        if (wid == 0) { LOADP((8*q1 + 8) & 63, A); STEP16(B); }
        else          produce_piped(16*q1 + 32);
        __syncthreads();
    }
    // ---- phase 18: steps [288,304); load slots [304,320) ----
    if (wid == 0) { LOADP((8*18 + 8) & 63, B); STEP16(A); }
    else          produce_piped(16*18 + 32);   // rows >= 318: none
    __syncthreads();
    // ---- phase 19: steps [304,318) = 14 steps (7 pairs) ----
    if (wid == 0) {
        #pragma unroll
        for (int i = 0; i < 7; ++i) { STEP(B[i].x, B[i].y); STEP(B[i].z, B[i].w); }
        // K[255][255] = lane 63's kup2 (col j = 4*63+2+1 = 255)
        if (lane == 63) atomicAdd(out, w * kup2);
    }
}

extern "C" void kernel_launch(void* const* d_in, const int* in_sizes, int n_in,
                              void* d_out, int out_size, void* d_ws, size_t ws_size,
                              hipStream_t stream) {
    const float* X = (const float*)d_in[0];
    const float* Y = (const float*)d_in[1];
    float* out = (float*)d_out;
    hipMemsetAsync(out, 0, sizeof(float), stream);
    sig_fused<<<dim3(3 * NA), dim3(256), 0, stream>>>(X, Y, out);
}